// Round 1
// baseline (662.369 us; speedup 1.0000x reference)
//
#include <hip/hip_runtime.h>

// HydraBackbonePlus: 10 dilations x {X, diffX} x 32 groups, 9-tap grouped dilated
// conv (8 out-ch per group), per-position argmax/argmin over the 8 channels,
// histogram-reduced to (32, 1280, 8) with relu.
//
// Strategy: residue-space decomposition l = r + m*d so the conv is contiguous
// in m (halo 8) for every dilation. Block = (di, j, b, residue-chunk, m-chunk),
// stages 12-channel X tile into LDS (zero-padded), 256 threads = 32 groups x 8,
// each thread slides a 12-float register window over 128 positions.

#define NDIL  10
#define NB    32     // batch
#define CIN   12
#define SEQ   8192
#define NG    32     // groups
#define CPER  6      // channels gathered per group
#define OUTCH 1280   // 10*2*2*32

__global__ __launch_bounds__(256, 2) void hydra_main(
    const float* __restrict__ X, const float* __restrict__ W,
    const int* __restrict__ I, float* __restrict__ out) {

  __shared__ float Xs[15408];  // max: 12 * (32*40 + 4) floats = 61632 B

  // ---- decode blockIdx -> (di, j, b, rc, mcid) ----
  int rem = blockIdx.x;
  int di = 0, j = 0;
  int d, R, TM, RC, MC, L;
  for (;;) {
    d = 1 << di;
    R = d < 32 ? d : 32;
    TM = 1024 / R;
    RC = d / R;
    L = SEQ - j;
    int Mmax = (L + d - 1) / d;
    MC = (Mmax + TM - 1) / TM;
    int nb = NB * RC * MC;
    if (rem < nb) break;
    rem -= nb;
    ++j;
    if (j == 2) { j = 0; ++di; }
    if (di >= NDIL) return;
  }
  int b = rem / (RC * MC);
  int r2 = rem % (RC * MC);
  int rc = r2 / MC;
  int mcid = r2 % MC;

  int rbits = (di < 5) ? di : 5;  // log2(R)
  int SR = TM + 8;                // row stride (floats), multiple of 4
  int CS = R * SR + 4;            // channel stride, +4 keeps 16B align & shifts bank phase
  int r0 = rc * R;
  int m0 = mcid * TM;
  int tid = threadIdx.x;

  // ---- stage X (or diffX) tile into LDS, zero-padded ----
  for (int ch = 0; ch < CIN; ++ch) {
    const float* xb = X + ((size_t)b * CIN + ch) * SEQ;
    float* dst = Xs + ch * CS;
    int perch = R * SR;
    for (int f = tid; f < perch; f += 256) {
      int rr = f & (R - 1);
      int mm = f >> rbits;
      int mp = m0 + mm - 4;
      int pos = r0 + rr + mp * d;
      float v = 0.f;
      if (mp >= 0 && pos < L)
        v = (j == 0) ? xb[pos] : (xb[pos + 1] - xb[pos]);
      dst[rr * SR + mm] = v;
    }
  }
  __syncthreads();

  // ---- per-thread setup: group, weights (72 regs), channel bases ----
  int g = tid >> 3, s = tid & 7;
  float Wr[8][9];
  {
    const float* wp = W + (size_t)((di * 2 + j) * 256 + g * 8) * 9;
#pragma unroll
    for (int k = 0; k < 8; ++k)
#pragma unroll
      for (int t = 0; t < 9; ++t) Wr[k][t] = wp[k * 9 + t];
  }
  const float* base[CPER];
  {
    const int* ip = I + ((di * 2 + j) * NG + g) * CPER;
#pragma unroll
    for (int i = 0; i < CPER; ++i) base[i] = Xs + ip[i] * CS;
  }

  float cmx[8] = {0.f, 0.f, 0.f, 0.f, 0.f, 0.f, 0.f, 0.f};
  float cmn[8] = {0.f, 0.f, 0.f, 0.f, 0.f, 0.f, 0.f, 0.f};

  int rpt, CL;
  if (R >= 8) { rpt = R >> 3; CL = TM; }
  else        { rpt = 1;      CL = TM >> (3 - rbits); }   // = TM*R/8

  for (int rep = 0; rep < rpt; ++rep) {
    int rr, mst;
    if (R >= 8) { rr = s + (rep << 3); mst = 0; }
    else        { rr = s & (R - 1);    mst = (s >> rbits) * CL; }
    int rowoff = rr * SR + mst;
    int pos = (r0 + rr) + (m0 + mst) * d;

    auto ldsum = [&](int idx) {
      float4 r = *reinterpret_cast<const float4*>(base[0] + idx);
#pragma unroll
      for (int i = 1; i < CPER; ++i) {
        float4 t = *reinterpret_cast<const float4*>(base[i] + idx);
        r.x += t.x; r.y += t.y; r.z += t.z; r.w += t.w;
      }
      return r;
    };

    float4 w0 = ldsum(rowoff + 0);
    float4 w1 = ldsum(rowoff + 4);
    for (int st = 0; st < CL; st += 4) {
      float4 w2 = ldsum(rowoff + st + 8);
      float win[12] = {w0.x, w0.y, w0.z, w0.w,
                       w1.x, w1.y, w1.z, w1.w,
                       w2.x, w2.y, w2.z, w2.w};
#pragma unroll
      for (int p = 0; p < 4; ++p) {
        float z[8];
#pragma unroll
        for (int k = 0; k < 8; ++k) {
          float acc = Wr[k][0] * win[p];
#pragma unroll
          for (int t = 1; t < 9; ++t) acc = fmaf(Wr[k][t], win[p + t], acc);
          z[k] = acc;
        }
        if (pos < L) {
          float mx = fmaxf(fmaxf(fmaxf(z[0], z[1]), fmaxf(z[2], z[3])),
                           fmaxf(fmaxf(z[4], z[5]), fmaxf(z[6], z[7])));
          float mn = fminf(fminf(fminf(z[0], z[1]), fminf(z[2], z[3])),
                           fminf(fminf(z[4], z[5]), fminf(z[6], z[7])));
#pragma unroll
          for (int k = 0; k < 8; ++k) {
            cmx[k] += (z[k] == mx) ? z[k] : 0.f;
            cmn[k] += (z[k] == mn) ? 1.f : 0.f;
          }
        }
        pos += d;
      }
      w0 = w1; w1 = w2;
    }
  }

  // ---- reduce across the 8 threads of each group (consecutive lanes) ----
#pragma unroll
  for (int k = 0; k < 8; ++k) {
#pragma unroll
    for (int off = 4; off > 0; off >>= 1) {
      cmx[k] += __shfl_down(cmx[k], off);
      cmn[k] += __shfl_down(cmn[k], off);
    }
  }
  if (s == 0) {
    int cbase = (di * 2 + j) * 64;
    float* om = out + ((size_t)b * OUTCH + cbase + g) * 8;
    float* on = out + ((size_t)b * OUTCH + cbase + 32 + g) * 8;
#pragma unroll
    for (int k = 0; k < 8; ++k) {
      atomicAdd(om + k, cmx[k]);
      atomicAdd(on + k, cmn[k]);
    }
  }
}

__global__ void hydra_relu(float* __restrict__ out, int n) {
  int i = blockIdx.x * 256 + threadIdx.x;
  if (i < n) out[i] = fmaxf(out[i], 0.f);
}

extern "C" void kernel_launch(void* const* d_in, const int* in_sizes, int n_in,
                              void* d_out, int out_size, void* d_ws, size_t ws_size,
                              hipStream_t stream) {
  const float* X = (const float*)d_in[0];
  const float* W = (const float*)d_in[1];
  const int*   I = (const int*)d_in[2];
  float* out = (float*)d_out;

  // zero the accumulation target (harness poisons it with 0xAA)
  hipMemsetAsync(d_out, 0, (size_t)out_size * sizeof(float), stream);

  // grid size: mirror of the in-kernel decode loop
  int total = 0;
  for (int di = 0; di < NDIL; ++di) {
    int d = 1 << di, R = d < 32 ? d : 32, TM = 1024 / R, RC = d / R;
    for (int j = 0; j < 2; ++j) {
      int L = SEQ - j;
      int Mmax = (L + d - 1) / d;
      int MC = (Mmax + TM - 1) / TM;
      total += NB * RC * MC;
    }
  }

  hydra_main<<<total, 256, 0, stream>>>(X, W, I, out);
  hydra_relu<<<(out_size + 255) / 256, 256, 0, stream>>>(out, out_size);
}